// Round 4
// baseline (1603.353 us; speedup 1.0000x reference)
//
#include <hip/hip_runtime.h>
#include <stdint.h>

// Problem constants: B=128, S=256, H=512
#define B_ 128
#define S_ 256
#define H_ 512

typedef __attribute__((ext_vector_type(4))) float f32x4;
typedef __attribute__((ext_vector_type(4))) int i32x4;
typedef __attribute__((ext_vector_type(2))) unsigned int u32x2;
typedef __attribute__((ext_vector_type(8))) __bf16 bf16x8;
typedef unsigned long long u64;

// ---------- workspace layout (bytes) ----------
#define OFF_G      0          // 32768 f32 = 131072 B
#define OFF_RSR    131072     // 512 f32
#define OFF_RSH    133120     // 512 f32
#define OFF_EX     135168     // 2 parity x 8 groups x (16 rows x 512 n) dwords = 524288 B
#define OFF_BP     659456     // z1_w packed bf16 = 2097152 B
#define OFF_CBUF   659456     // alias BP: Cb written by k_scan AFTER k_gate read BP
#define OFF_PB     2756608    // scan weights packed bf16 = 1048576 B
#define OFF_LOGITS 3805184    // 32768 f32 = 131072 B (dedicated: gate->softmax)
// total 3936256 B ~ 3.75 MB

__device__ __forceinline__ unsigned short f2bf(float f) {
  unsigned u = __builtin_bit_cast(unsigned, f);
  u += 0x7FFFu + ((u >> 16) & 1u);
  return (unsigned short)(u >> 16);
}
__device__ __forceinline__ float fast_sigmoid(float x) {
  return 1.0f / (1.0f + __expf(-x));
}
__device__ __forceinline__ float fast_tanh(float x) {
  return 1.0f - 2.0f / (__expf(2.0f * x) + 1.0f);
}

// ---------------------------------------------------------------------------
// Prep 1: pack z1_w (2048x512 f32) -> bf16, layout Bp[(k>>3)*512+n][k&7]
// ---------------------------------------------------------------------------
__global__ void k_prep_bp(const float* __restrict__ z1w,
                          unsigned short* __restrict__ Bp) {
  int t = blockIdx.x * blockDim.x + threadIdx.x;  // < 2048*512
  int k = t >> 9, n = t & 511;
  Bp[((k >> 3) * 512 + n) * 8 + (k & 7)] = f2bf(z1w[t]);
}

// ---------------------------------------------------------------------------
// Prep 2: pack Ur,U into per-(mem 0..7, wave 0..7, ktile 0..15, lane) MFMA
// B-fragments. mat = w>>2 (0=Ur,1=U), nt = w&3; n = mem*64 + nt*16 + (l&15).
// ---------------------------------------------------------------------------
__global__ void k_prep_pb(const float* __restrict__ Ur,
                          const float* __restrict__ U,
                          unsigned short* __restrict__ PB) {
  int t = blockIdx.x * blockDim.x + threadIdx.x;  // < 524288
  int j = t & 7;
  int l = (t >> 3) & 63;
  int kt = (t >> 9) & 15;
  int w = (t >> 13) & 7;
  int mem = t >> 16;  // 0..7
  int k = kt * 32 + ((l >> 4) & 3) * 8 + j;
  int n = mem * 64 + (w & 3) * 16 + (l & 15);
  const float* src = (w >> 2) ? U : Ur;
  PB[t] = f2bf(src[k * 512 + n]);
}

// ---------------------------------------------------------------------------
// Prep 3: row sums of Wr and W ('bsh,hk->bsh' collapses to these)
// ---------------------------------------------------------------------------
__global__ void k_prep_rs(const float* __restrict__ Wr,
                          const float* __restrict__ W,
                          float* __restrict__ rsr, float* __restrict__ rsh) {
  __shared__ float red[4];
  int h2 = blockIdx.x;
  int t = threadIdx.x;
  const float* M = (h2 >= 512) ? W : Wr;
  int h = h2 & 511;
  float sv = M[h * 512 + t] + M[h * 512 + 256 + t];
#pragma unroll
  for (int mask = 1; mask < 64; mask <<= 1) sv += __shfl_xor(sv, mask, 64);
  if ((t & 63) == 0) red[t >> 6] = sv;
  __syncthreads();
  if (t == 0) {
    float tot = red[0] + red[1] + red[2] + red[3];
    ((h2 >= 512) ? rsh : rsr)[h] = tot;
  }
}

// ---------------------------------------------------------------------------
// Gate GEMM + fused tanh/dot epilogue (unchanged — will profile next round)
// ---------------------------------------------------------------------------
__global__ __launch_bounds__(512, 4) void k_gate(
    const float* __restrict__ facts, const float* __restrict__ questions,
    const float* __restrict__ prevM, const float* __restrict__ z1b,
    const float* __restrict__ z2w, const unsigned short* __restrict__ Bp,
    float* __restrict__ logits) {
  __shared__ float qS[512], mS[512], z1bS[512], z2wS[512];
  __shared__ unsigned short At[64 * 40];
  __shared__ unsigned short Bt[16384];
  __shared__ float lp[64 * 4];
  const int tid = threadIdx.x;
  const int row0 = blockIdx.x * 64;
  const int b = row0 >> 8;
  const int s0 = row0 & 255;
  qS[tid] = questions[b * 512 + tid];
  mS[tid] = prevM[b * 512 + tid];
  z1bS[tid] = z1b[tid];
  z2wS[tid] = z2w[tid];
  const int w = tid >> 6, l = tid & 63;
  const int mgrp = w & 1, ngrp = w >> 1;
  const int lm = l & 15, lk = l >> 4;
  f32x4 acc[2][8];
#pragma unroll
  for (int a = 0; a < 2; ++a)
#pragma unroll
    for (int i = 0; i < 8; ++i) acc[a][i] = (f32x4){0.f, 0.f, 0.f, 0.f};
  const int arow = tid >> 3, ac = tid & 7;
  const float* fbase = facts + ((size_t)(b * 256 + s0 + arow)) * 512 + ac * 4;

  for (int kb = 0; kb < 64; ++kb) {
    __syncthreads();
    const int part = kb >> 4;          // 0: f*q, 1: f*m, 2: |f-q|, 3: |f-m|
    const int h0 = (kb & 15) * 32;
    f32x4 fv = *(const f32x4*)(fbase + h0);
    f32x4 ov = (part & 1) ? *(const f32x4*)&mS[h0 + ac * 4]
                          : *(const f32x4*)&qS[h0 + ac * 4];
    float z0, z1, z2, z3;
    if (part < 2) {
      z0 = fv[0] * ov[0]; z1 = fv[1] * ov[1];
      z2 = fv[2] * ov[2]; z3 = fv[3] * ov[3];
    } else {
      z0 = fabsf(fv[0] - ov[0]); z1 = fabsf(fv[1] - ov[1]);
      z2 = fabsf(fv[2] - ov[2]); z3 = fabsf(fv[3] - ov[3]);
    }
    unsigned p0 = (unsigned)f2bf(z0) | ((unsigned)f2bf(z1) << 16);
    unsigned p1 = (unsigned)f2bf(z2) | ((unsigned)f2bf(z3) << 16);
    u32x2 pk = {p0, p1};
    *(u32x2*)&At[arow * 40 + ac * 4] = pk;
    const char* bsrc = (const char*)Bp + (size_t)kb * 32768;
#pragma unroll
    for (int i = 0; i < 4; ++i)
      *(i32x4*)((char*)Bt + i * 8192 + tid * 16) =
          *(const i32x4*)(bsrc + i * 8192 + tid * 16);
    __syncthreads();
    bf16x8 af[2];
#pragma unroll
    for (int mi = 0; mi < 2; ++mi) {
      i32x4 av = *(const i32x4*)&At[((mgrp * 2 + mi) * 16 + lm) * 40 + lk * 8];
      af[mi] = __builtin_bit_cast(bf16x8, av);
    }
#pragma unroll
    for (int i = 0; i < 8; ++i) {
      const int nt = ngrp * 8 + i;
      i32x4 bv = *(const i32x4*)&Bt[lk * 4096 + (nt * 16 + lm) * 8];
      bf16x8 bf = __builtin_bit_cast(bf16x8, bv);
      acc[0][i] = __builtin_amdgcn_mfma_f32_16x16x32_bf16(af[0], bf, acc[0][i], 0, 0, 0);
      acc[1][i] = __builtin_amdgcn_mfma_f32_16x16x32_bf16(af[1], bf, acc[1][i], 0, 0, 0);
    }
  }
  float pr_[2][4];
#pragma unroll
  for (int mi = 0; mi < 2; ++mi)
#pragma unroll
    for (int r = 0; r < 4; ++r) pr_[mi][r] = 0.f;
#pragma unroll
  for (int i = 0; i < 8; ++i) {
    const int n_i = (ngrp * 8 + i) * 16 + lm;
    const float zb = z1bS[n_i], zw = z2wS[n_i];
#pragma unroll
    for (int mi = 0; mi < 2; ++mi)
#pragma unroll
      for (int r = 0; r < 4; ++r)
        pr_[mi][r] += fast_tanh(acc[mi][i][r] + zb) * zw;
  }
#pragma unroll
  for (int mask = 1; mask < 16; mask <<= 1)
#pragma unroll
    for (int mi = 0; mi < 2; ++mi)
#pragma unroll
      for (int r = 0; r < 4; ++r)
        pr_[mi][r] += __shfl_xor(pr_[mi][r], mask, 64);
  if (lm == 0) {
#pragma unroll
    for (int mi = 0; mi < 2; ++mi)
#pragma unroll
      for (int r = 0; r < 4; ++r)
        lp[((mgrp * 2 + mi) * 16 + lk * 4 + r) * 4 + ngrp] = pr_[mi][r];
  }
  __syncthreads();
  if (tid < 64)
    logits[row0 + tid] =
        lp[tid * 4] + lp[tid * 4 + 1] + lp[tid * 4 + 2] + lp[tid * 4 + 3];
}

// ---------------------------------------------------------------------------
// Softmax over S per batch (z2_b dropped: shift-invariant, exact)
// ---------------------------------------------------------------------------
__global__ void k_softmax(const float* __restrict__ logits,
                          float* __restrict__ G) {
  __shared__ float red[4], red2[4];
  int b = blockIdx.x, t = threadIdx.x;
  float v = logits[b * 256 + t];
  float mx = v;
#pragma unroll
  for (int mask = 1; mask < 64; mask <<= 1)
    mx = fmaxf(mx, __shfl_xor(mx, mask, 64));
  if ((t & 63) == 0) red[t >> 6] = mx;
  __syncthreads();
  mx = fmaxf(fmaxf(red[0], red[1]), fmaxf(red[2], red[3]));
  float e = __expf(v - mx);
  float sm = e;
#pragma unroll
  for (int mask = 1; mask < 64; mask <<= 1) sm += __shfl_xor(sm, mask, 64);
  if ((t & 63) == 0) red2[t >> 6] = sm;
  __syncthreads();
  sm = red2[0] + red2[1] + red2[2] + red2[3];
  G[b * 256 + t] = e / sm;
}

// ---------------------------------------------------------------------------
// Scan v4: SELF-TAGGING exchange — one fabric hop on the critical path.
// 8 groups x 8 member-WGs, 16 batches/group. WG 'mem' owns n-slice
// [mem*64, mem*64+64); weights VGPR-resident. Exchange dword =
// bf16(C)<<16 | (s+1): readiness and payload in one load (no flags, no
// vmcnt-drain hop, no separate gather). Consumer thread t owns column n=t
// (16 dwords, one per batch row): gang-load 16, scatter hits to LDS,
// sleep-retry pending. Own-slice columns arrive via direct LDS writes.
// Parity double-buffer WAR-safe by induction; tags 1..256 never alias the
// 0xAA ws-poison (0xAAAA). Only 2 barriers/step.
// ---------------------------------------------------------------------------
__global__ __launch_bounds__(512, 1) void k_scan(
    const float* __restrict__ facts, const float* __restrict__ Gm,
    const unsigned short* __restrict__ PB, const float* __restrict__ rsr,
    const float* __restrict__ rsh, const float* __restrict__ br,
    const float* __restrict__ bur, const float* __restrict__ bw,
    const float* __restrict__ bu, unsigned int* __restrict__ EX,
    float* __restrict__ Cb) {
  __shared__ unsigned short A[16 * 520];  // 16 rows x 512 bf16, 1040B pitch
  __shared__ float outb[8 * 272];         // [w][row16 pitch17]
  const int tid = threadIdx.x;
  const int g = blockIdx.x & 7;    // group (same XCD under %8 round-robin)
  const int mem = blockIdx.x >> 3; // member / n-slice owner
  const int w = tid >> 6, l = tid & 63;
  const int lm = l & 15, lk = (l >> 4) & 3;
  // zero A
  for (int i = tid; i < 16 * 520 / 4; i += 512) ((u64*)A)[i] = 0ull;
  // weight fragments resident in VGPRs: this wave = (mat = w>>2, nt = w&3)
  i32x4 bfr[16];
  const char* pb = (const char*)PB + (size_t)(mem * 8 + w) * 16384;
#pragma unroll
  for (int kt = 0; kt < 16; ++kt)
    bfr[kt] = *(const i32x4*)(pb + kt * 1024 + l * 16);
  // producer lane (tid<256): thread owns (bb, 4 consecutive n)
  const int bb = tid >> 4;          // 0..15
  const int nq = tid & 15;          // n-quad within slice
  const int n0 = mem * 64 + nq * 4; // global n base
  const int batch = g * 16 + bb;
  f32x4 c_rsr, c_br, c_rsh, c_bw, c_bur, c_bu;
  const float* fptr = nullptr;
  const float* gptr = nullptr;
  if (tid < 256) {
    c_rsr = *(const f32x4*)(rsr + n0);
    c_br  = *(const f32x4*)(br + n0);
    c_rsh = *(const f32x4*)(rsh + n0);
    c_bw  = *(const f32x4*)(bw + n0);
    c_bur = *(const f32x4*)(bur + n0);
    c_bu  = *(const f32x4*)(bu + n0);
    fptr = facts + (size_t)batch * 256 * 512 + n0;
    gptr = Gm + batch * 256;
  }
  // consumer column: n = tid; own-window columns skip polling entirely
  const bool ownCol = ((tid >> 6) == mem);
  unsigned short* colA = (unsigned short*)((char*)A + tid * 2);  // + i*1040
  f32x4 Cv = (f32x4){0.f, 0.f, 0.f, 0.f};
  __syncthreads();

  for (int s = 0; s < 256; ++s) {
    const unsigned tag = (unsigned)(s + 1);
    const unsigned base = ((unsigned)(s & 1) * 8 + (unsigned)g) * 8192;
    // prefetch elementwise inputs (overlap with MFMA)
    f32x4 fct;
    float gval = 0.f;
    if (tid < 256) {
      fct = *(const f32x4*)(fptr + (size_t)s * 512);
      gval = gptr[s];
    }
    // ---- matvec: (C @ Ur | C @ U) slice via MFMA, two ILP chains ----
    f32x4 acc0 = (f32x4){0.f, 0.f, 0.f, 0.f};
    f32x4 acc1 = (f32x4){0.f, 0.f, 0.f, 0.f};
#pragma unroll
    for (int kt = 0; kt < 16; ++kt) {
      i32x4 av = *(const i32x4*)&A[lm * 520 + kt * 32 + lk * 8];
      bf16x8 afv = __builtin_bit_cast(bf16x8, av);
      bf16x8 bfv = __builtin_bit_cast(bf16x8, bfr[kt]);
      if (kt & 1)
        acc1 = __builtin_amdgcn_mfma_f32_16x16x32_bf16(afv, bfv, acc1, 0, 0, 0);
      else
        acc0 = __builtin_amdgcn_mfma_f32_16x16x32_bf16(afv, bfv, acc0, 0, 0, 0);
    }
    f32x4 accs = acc0 + acc1;
#pragma unroll
    for (int r = 0; r < 4; ++r)
      outb[w * 272 + (lk * 4 + r) * 17 + lm] = accs[r];
    __syncthreads();  // outb ready; A's step-s MFMA reads complete
    // ---- elementwise update + tagged publish (tid<256) ----
    if (tid < 256) {
      unsigned short pk[4];
#pragma unroll
      for (int r = 0; r < 4; ++r) {
        const int n_loc = nq * 4 + r;
        const float uro = outb[(n_loc >> 4) * 272 + bb * 17 + (n_loc & 15)];
        const float uuo = outb[(4 + (n_loc >> 4)) * 272 + bb * 17 + (n_loc & 15)];
        const float pr = fct[r] * c_rsr[r] + c_br[r];
        const float ph = fct[r] * c_rsh[r] + c_bw[r];
        const float r_ = fast_sigmoid(pr + uro + c_bur[r]);
        const float ht = fast_tanh(ph + r_ * (uuo + c_bu[r]));
        Cv[r] = gval * ht + (1.0f - gval) * Cv[r];
        pk[r] = f2bf(Cv[r]);
      }
      // publish first (stores start their fabric flight ASAP)
      const u64 q0 = (u64)(((unsigned)pk[0] << 16) | tag) |
                     ((u64)(((unsigned)pk[1] << 16) | tag) << 32);
      const u64 q1 = (u64)(((unsigned)pk[2] << 16) | tag) |
                     ((u64)(((unsigned)pk[3] << 16) | tag) << 32);
      u64* dst = (u64*)(EX + base + (unsigned)bb * 512 + (unsigned)n0);
      __hip_atomic_store(dst, q0, __ATOMIC_RELAXED, __HIP_MEMORY_SCOPE_AGENT);
      __hip_atomic_store(dst + 1, q1, __ATOMIC_RELAXED, __HIP_MEMORY_SCOPE_AGENT);
      // own slice straight into A-LDS (covers all own-window columns)
      const u64 word = (u64)pk[0] | ((u64)pk[1] << 16) | ((u64)pk[2] << 32) |
                       ((u64)pk[3] << 48);
      *(u64*)((char*)A + bb * 1040 + n0 * 2) = word;
    }
    // ---- self-tagged poll-gather: column n=tid, 16 rows ----
    if (!ownCol) {
      const unsigned* src = EX + base + (unsigned)tid;
      if (tid >= 256) __builtin_amdgcn_s_sleep(4);  // align 1st burst w/ pubs
      unsigned vbuf[16];
#pragma unroll
      for (int i = 0; i < 16; ++i)
        vbuf[i] = __hip_atomic_load(src + i * 512, __ATOMIC_RELAXED,
                                    __HIP_MEMORY_SCOPE_AGENT);
      unsigned pending = 0;
#pragma unroll
      for (int i = 0; i < 16; ++i) {
        if ((vbuf[i] & 0xFFFFu) == tag)
          colA[i * 520] = (unsigned short)(vbuf[i] >> 16);
        else
          pending |= 1u << i;
      }
      int guard = 0;
      while (pending) {
        __builtin_amdgcn_s_sleep(1);
        unsigned np = pending;
#pragma unroll
        for (int i = 0; i < 16; ++i) {
          if ((np >> i) & 1u) {
            unsigned v = __hip_atomic_load(src + i * 512, __ATOMIC_RELAXED,
                                           __HIP_MEMORY_SCOPE_AGENT);
            if ((v & 0xFFFFu) == tag) {
              colA[i * 520] = (unsigned short)(v >> 16);
              np &= ~(1u << i);
            }
          }
        }
        pending = np;
        if (++guard > (1 << 22)) break;  // hang-safety bailout
      }
    }
    __syncthreads();  // A fully assembled for next step
  }
  if (tid < 256) *(f32x4*)(Cb + (size_t)batch * 512 + n0) = Cv;
}

// ---------------------------------------------------------------------------
// Final: out[b] = relu([prevM | C | questions] @ nm_w + nm_b). 2 batches/WG.
// ---------------------------------------------------------------------------
__global__ __launch_bounds__(512) void k_final(
    const float* __restrict__ prevM, const float* __restrict__ questions,
    const float* __restrict__ Cb, const float* __restrict__ nmw,
    const float* __restrict__ nmb, float* __restrict__ out) {
  __shared__ float cc[2][1536];
  const int t = threadIdx.x;
  const int b0 = blockIdx.x * 2;
  for (int i = t; i < 1536; i += 512) {
#pragma unroll
    for (int bi = 0; bi < 2; ++bi) {
      int bbx = b0 + bi;
      float v;
      if (i < 512) v = prevM[bbx * 512 + i];
      else if (i < 1024) v = Cb[bbx * 512 + i - 512];
      else v = questions[bbx * 512 + i - 1024];
      cc[bi][i] = v;
    }
  }
  __syncthreads();
  const int h = t;
  float a0 = nmb[h], a1 = nmb[h];
#pragma unroll 4
  for (int f = 0; f < 1536; ++f) {
    float wv = nmw[f * 512 + h];
    a0 = fmaf(cc[0][f], wv, a0);
    a1 = fmaf(cc[1][f], wv, a1);
  }
  out[(size_t)b0 * 512 + h] = fmaxf(a0, 0.f);
  out[(size_t)(b0 + 1) * 512 + h] = fmaxf(a1, 0.f);
}

// ---------------------------------------------------------------------------
extern "C" void kernel_launch(void* const* d_in, const int* in_sizes, int n_in,
                              void* d_out, int out_size, void* d_ws,
                              size_t ws_size, hipStream_t stream) {
  const float* facts     = (const float*)d_in[0];
  const float* questions = (const float*)d_in[1];
  const float* prevM     = (const float*)d_in[2];
  const float* z1w       = (const float*)d_in[3];
  const float* z1b       = (const float*)d_in[4];
  const float* z2w       = (const float*)d_in[5];
  // d_in[6] = z2_b: softmax shift-invariant, unused (exact)
  const float* Wr        = (const float*)d_in[7];
  const float* br        = (const float*)d_in[8];
  const float* Ur        = (const float*)d_in[9];
  const float* bur       = (const float*)d_in[10];
  const float* W         = (const float*)d_in[11];
  const float* bw        = (const float*)d_in[12];
  const float* U         = (const float*)d_in[13];
  const float* bu        = (const float*)d_in[14];
  const float* nmw       = (const float*)d_in[15];
  const float* nmb       = (const float*)d_in[16];

  char* ws = (char*)d_ws;
  float* G             = (float*)(ws + OFF_G);
  float* rsr           = (float*)(ws + OFF_RSR);
  float* rsh           = (float*)(ws + OFF_RSH);
  unsigned* EX         = (unsigned*)(ws + OFF_EX);
  float* Cb            = (float*)(ws + OFF_CBUF);
  float* logits        = (float*)(ws + OFF_LOGITS);
  unsigned short* Bp   = (unsigned short*)(ws + OFF_BP);
  unsigned short* PB   = (unsigned short*)(ws + OFF_PB);

  k_prep_bp<<<2048, 512, 0, stream>>>(z1w, Bp);
  k_prep_pb<<<1024, 512, 0, stream>>>(Ur, U, PB);
  k_prep_rs<<<1024, 256, 0, stream>>>(Wr, W, rsr, rsh);
  k_gate<<<512, 512, 0, stream>>>(facts, questions, prevM, z1b, z2w, Bp, logits);
  k_softmax<<<128, 256, 0, stream>>>(logits, G);
  k_scan<<<64, 512, 0, stream>>>(facts, G, PB, rsr, rsh, br, bur, bw, bu, EX, Cb);
  k_final<<<64, 512, 0, stream>>>(prevM, questions, Cb, nmw, nmb, (float*)d_out);
}

// Round 5
// 1405.437 us; speedup vs baseline: 1.1408x; 1.1408x over previous
//
#include <hip/hip_runtime.h>
#include <stdint.h>

// Problem constants: B=128, S=256, H=512
#define B_ 128
#define S_ 256
#define H_ 512

typedef __attribute__((ext_vector_type(4))) float f32x4;
typedef __attribute__((ext_vector_type(4))) int i32x4;
typedef __attribute__((ext_vector_type(2))) unsigned int u32x2;
typedef __attribute__((ext_vector_type(8))) __bf16 bf16x8;
typedef unsigned long long u64;

// ---------- workspace layout (bytes) ----------
#define OFF_G      0          // 32768 f32 = 131072 B
#define OFF_RSR    131072     // 512 f32
#define OFF_RSH    133120     // 512 f32
#define OFF_EX     135168     // 2 parity x 8 groups x (16 rows x 512 n) dwords = 524288 B
#define OFF_BP     659456     // z1_w packed bf16 = 2097152 B
#define OFF_CBUF   659456     // alias BP: Cb written by k_scan AFTER k_gate read BP
#define OFF_PB     2756608    // scan weights packed bf16 = 1048576 B
#define OFF_LOGITS 3805184    // 32768 f32 = 131072 B (dedicated: gate->softmax)
// total 3936256 B ~ 3.75 MB

__device__ __forceinline__ unsigned short f2bf(float f) {
  unsigned u = __builtin_bit_cast(unsigned, f);
  u += 0x7FFFu + ((u >> 16) & 1u);
  return (unsigned short)(u >> 16);
}
__device__ __forceinline__ float fast_sigmoid(float x) {
  return 1.0f / (1.0f + __expf(-x));
}
__device__ __forceinline__ float fast_tanh(float x) {
  return 1.0f - 2.0f / (__expf(2.0f * x) + 1.0f);
}

// ---------------------------------------------------------------------------
// Prep 1: pack z1_w (2048x512 f32) -> bf16, layout Bp[(k>>3)*512+n][k&7]
// ---------------------------------------------------------------------------
__global__ void k_prep_bp(const float* __restrict__ z1w,
                          unsigned short* __restrict__ Bp) {
  int t = blockIdx.x * blockDim.x + threadIdx.x;  // < 2048*512
  int k = t >> 9, n = t & 511;
  Bp[((k >> 3) * 512 + n) * 8 + (k & 7)] = f2bf(z1w[t]);
}

// ---------------------------------------------------------------------------
// Prep 2: pack Ur,U into per-(mem 0..3, wave 0..7, jn 0..1, ktile, lane) MFMA
// B-fragments. mat = w>>2 (0=Ur,1=U); n = mem*128 + ((w&3)*2+jn)*16 + (l&15).
// ---------------------------------------------------------------------------
__global__ void k_prep_pb(const float* __restrict__ Ur,
                          const float* __restrict__ U,
                          unsigned short* __restrict__ PB) {
  int t = blockIdx.x * blockDim.x + threadIdx.x;  // < 524288
  int j = t & 7;
  int l = (t >> 3) & 63;
  int kt = (t >> 9) & 15;
  int jn = (t >> 13) & 1;
  int w = (t >> 14) & 7;
  int mem = t >> 17;  // 0..3
  int k = kt * 32 + ((l >> 4) & 3) * 8 + j;
  int n = mem * 128 + ((w & 3) * 2 + jn) * 16 + (l & 15);
  const float* src = (w >> 2) ? U : Ur;
  PB[t] = f2bf(src[k * 512 + n]);
}

// ---------------------------------------------------------------------------
// Prep 3: row sums of Wr and W ('bsh,hk->bsh' collapses to these)
// ---------------------------------------------------------------------------
__global__ void k_prep_rs(const float* __restrict__ Wr,
                          const float* __restrict__ W,
                          float* __restrict__ rsr, float* __restrict__ rsh) {
  __shared__ float red[4];
  int h2 = blockIdx.x;
  int t = threadIdx.x;
  const float* M = (h2 >= 512) ? W : Wr;
  int h = h2 & 511;
  float sv = M[h * 512 + t] + M[h * 512 + 256 + t];
#pragma unroll
  for (int mask = 1; mask < 64; mask <<= 1) sv += __shfl_xor(sv, mask, 64);
  if ((t & 63) == 0) red[t >> 6] = sv;
  __syncthreads();
  if (t == 0) {
    float tot = red[0] + red[1] + red[2] + red[3];
    ((h2 >= 512) ? rsh : rsr)[h] = tot;
  }
}

// ---------------------------------------------------------------------------
// Gate GEMM + fused tanh/dot epilogue (unchanged)
// ---------------------------------------------------------------------------
__global__ __launch_bounds__(512, 4) void k_gate(
    const float* __restrict__ facts, const float* __restrict__ questions,
    const float* __restrict__ prevM, const float* __restrict__ z1b,
    const float* __restrict__ z2w, const unsigned short* __restrict__ Bp,
    float* __restrict__ logits) {
  __shared__ float qS[512], mS[512], z1bS[512], z2wS[512];
  __shared__ unsigned short At[64 * 40];
  __shared__ unsigned short Bt[16384];
  __shared__ float lp[64 * 4];
  const int tid = threadIdx.x;
  const int row0 = blockIdx.x * 64;
  const int b = row0 >> 8;
  const int s0 = row0 & 255;
  qS[tid] = questions[b * 512 + tid];
  mS[tid] = prevM[b * 512 + tid];
  z1bS[tid] = z1b[tid];
  z2wS[tid] = z2w[tid];
  const int w = tid >> 6, l = tid & 63;
  const int mgrp = w & 1, ngrp = w >> 1;
  const int lm = l & 15, lk = l >> 4;
  f32x4 acc[2][8];
#pragma unroll
  for (int a = 0; a < 2; ++a)
#pragma unroll
    for (int i = 0; i < 8; ++i) acc[a][i] = (f32x4){0.f, 0.f, 0.f, 0.f};
  const int arow = tid >> 3, ac = tid & 7;
  const float* fbase = facts + ((size_t)(b * 256 + s0 + arow)) * 512 + ac * 4;

  for (int kb = 0; kb < 64; ++kb) {
    __syncthreads();
    const int part = kb >> 4;          // 0: f*q, 1: f*m, 2: |f-q|, 3: |f-m|
    const int h0 = (kb & 15) * 32;
    f32x4 fv = *(const f32x4*)(fbase + h0);
    f32x4 ov = (part & 1) ? *(const f32x4*)&mS[h0 + ac * 4]
                          : *(const f32x4*)&qS[h0 + ac * 4];
    float z0, z1, z2, z3;
    if (part < 2) {
      z0 = fv[0] * ov[0]; z1 = fv[1] * ov[1];
      z2 = fv[2] * ov[2]; z3 = fv[3] * ov[3];
    } else {
      z0 = fabsf(fv[0] - ov[0]); z1 = fabsf(fv[1] - ov[1]);
      z2 = fabsf(fv[2] - ov[2]); z3 = fabsf(fv[3] - ov[3]);
    }
    unsigned p0 = (unsigned)f2bf(z0) | ((unsigned)f2bf(z1) << 16);
    unsigned p1 = (unsigned)f2bf(z2) | ((unsigned)f2bf(z3) << 16);
    u32x2 pk = {p0, p1};
    *(u32x2*)&At[arow * 40 + ac * 4] = pk;
    const char* bsrc = (const char*)Bp + (size_t)kb * 32768;
#pragma unroll
    for (int i = 0; i < 4; ++i)
      *(i32x4*)((char*)Bt + i * 8192 + tid * 16) =
          *(const i32x4*)(bsrc + i * 8192 + tid * 16);
    __syncthreads();
    bf16x8 af[2];
#pragma unroll
    for (int mi = 0; mi < 2; ++mi) {
      i32x4 av = *(const i32x4*)&At[((mgrp * 2 + mi) * 16 + lm) * 40 + lk * 8];
      af[mi] = __builtin_bit_cast(bf16x8, av);
    }
#pragma unroll
    for (int i = 0; i < 8; ++i) {
      const int nt = ngrp * 8 + i;
      i32x4 bv = *(const i32x4*)&Bt[lk * 4096 + (nt * 16 + lm) * 8];
      bf16x8 bf = __builtin_bit_cast(bf16x8, bv);
      acc[0][i] = __builtin_amdgcn_mfma_f32_16x16x32_bf16(af[0], bf, acc[0][i], 0, 0, 0);
      acc[1][i] = __builtin_amdgcn_mfma_f32_16x16x32_bf16(af[1], bf, acc[1][i], 0, 0, 0);
    }
  }
  float pr_[2][4];
#pragma unroll
  for (int mi = 0; mi < 2; ++mi)
#pragma unroll
    for (int r = 0; r < 4; ++r) pr_[mi][r] = 0.f;
#pragma unroll
  for (int i = 0; i < 8; ++i) {
    const int n_i = (ngrp * 8 + i) * 16 + lm;
    const float zb = z1bS[n_i], zw = z2wS[n_i];
#pragma unroll
    for (int mi = 0; mi < 2; ++mi)
#pragma unroll
      for (int r = 0; r < 4; ++r)
        pr_[mi][r] += fast_tanh(acc[mi][i][r] + zb) * zw;
  }
#pragma unroll
  for (int mask = 1; mask < 16; mask <<= 1)
#pragma unroll
    for (int mi = 0; mi < 2; ++mi)
#pragma unroll
      for (int r = 0; r < 4; ++r)
        pr_[mi][r] += __shfl_xor(pr_[mi][r], mask, 64);
  if (lm == 0) {
#pragma unroll
    for (int mi = 0; mi < 2; ++mi)
#pragma unroll
      for (int r = 0; r < 4; ++r)
        lp[((mgrp * 2 + mi) * 16 + lk * 4 + r) * 4 + ngrp] = pr_[mi][r];
  }
  __syncthreads();
  if (tid < 64)
    logits[row0 + tid] =
        lp[tid * 4] + lp[tid * 4 + 1] + lp[tid * 4 + 2] + lp[tid * 4 + 3];
}

// ---------------------------------------------------------------------------
// Softmax over S per batch (z2_b dropped: shift-invariant, exact)
// ---------------------------------------------------------------------------
__global__ void k_softmax(const float* __restrict__ logits,
                          float* __restrict__ G) {
  __shared__ float red[4], red2[4];
  int b = blockIdx.x, t = threadIdx.x;
  float v = logits[b * 256 + t];
  float mx = v;
#pragma unroll
  for (int mask = 1; mask < 64; mask <<= 1)
    mx = fmaxf(mx, __shfl_xor(mx, mask, 64));
  if ((t & 63) == 0) red[t >> 6] = mx;
  __syncthreads();
  mx = fmaxf(fmaxf(red[0], red[1]), fmaxf(red[2], red[3]));
  float e = __expf(v - mx);
  float sm = e;
#pragma unroll
  for (int mask = 1; mask < 64; mask <<= 1) sm += __shfl_xor(sm, mask, 64);
  if ((t & 63) == 0) red2[t >> 6] = sm;
  __syncthreads();
  sm = red2[0] + red2[1] + red2[2] + red2[3];
  G[b * 256 + t] = e / sm;
}

// ---------------------------------------------------------------------------
// Scan v5: 8 groups x 4 member-WGs (32 WGs), 16 batches/group, N=128/WG.
// Weights VGPR-resident (128 VGPR/lane). Exchange dword = bf16(C)<<16|(s+1):
// per-dword self-tagged (no drain, no flags, no separate gather pass).
// Consumer: ONE coalesced 8x8B burst/thread, then sleep(2)-throttled retry of
// PENDING units only (R4's failure was full-volume 64-cyc retry hammering).
// Parity double-buffer WAR-safe by induction; tags 1..256 never alias the
// 0xAA ws-poison (0xAAAA). 2 barriers/step.
// ---------------------------------------------------------------------------
__global__ __launch_bounds__(512, 1) void k_scan(
    const float* __restrict__ facts, const float* __restrict__ Gm,
    const unsigned short* __restrict__ PB, const float* __restrict__ rsr,
    const float* __restrict__ rsh, const float* __restrict__ br,
    const float* __restrict__ bur, const float* __restrict__ bw,
    const float* __restrict__ bu, unsigned int* __restrict__ EX,
    float* __restrict__ Cb) {
  __shared__ unsigned short A[16 * 520];  // 16 rows x 512 bf16, 1040B pitch
  __shared__ float outb[16 * 272];        // [tile16][row16 pitch17]
  const int tid = threadIdx.x;
  const int g = blockIdx.x & 7;    // group (same XCD under %8 round-robin)
  const int mem = blockIdx.x >> 3; // member 0..3, n-slice [mem*128, +128)
  const int w = tid >> 6, l = tid & 63;
  const int lm = l & 15, lk = (l >> 4) & 3;
  // zero A
  for (int i = tid; i < 16 * 520 / 4; i += 512) ((u64*)A)[i] = 0ull;
  // weight fragments resident in VGPRs: wave w = (mat = w>>2, ntile-pair w&3)
  i32x4 bfr[2][16];
  const char* pb = (const char*)PB + (size_t)(mem * 8 + w) * 32768;
#pragma unroll
  for (int jn = 0; jn < 2; ++jn)
#pragma unroll
    for (int kt = 0; kt < 16; ++kt)
      bfr[jn][kt] = *(const i32x4*)(pb + (jn * 16 + kt) * 1024 + l * 16);
  const int ot = (w >> 2) * 8 + (w & 3) * 2;  // outb tile base for this wave
  // producer lane: all 512 threads; thread owns (bb, 4 consecutive n)
  const int bb = tid >> 5;           // 0..15
  const int nqq = tid & 31;          // n-quad within slice
  const int n0 = mem * 128 + nqq * 4;
  const int nl0 = nqq * 4;           // n_loc base within slice
  const int batch = g * 16 + bb;
  const f32x4 c_rsr = *(const f32x4*)(rsr + n0);
  const f32x4 c_br  = *(const f32x4*)(br + n0);
  const f32x4 c_rsh = *(const f32x4*)(rsh + n0);
  const f32x4 c_bw  = *(const f32x4*)(bw + n0);
  const f32x4 c_bur = *(const f32x4*)(bur + n0);
  const f32x4 c_bu  = *(const f32x4*)(bu + n0);
  const float* fptr = facts + (size_t)batch * 256 * 512 + n0;
  const float* gptr = Gm + batch * 256;
  // consumer mapping: thread t polls u64 units u = i*512 + t (i=0..7) -> all
  // share column-pair cu = t&255 (dwords 2cu,2cu+1), rows i*2 + (t>>8).
  const int cu = tid & 255;
  const bool ownCol = ((cu >> 6) == mem);
  const int rbase = tid >> 8;  // 0 or 1
  f32x4 Cv = (f32x4){0.f, 0.f, 0.f, 0.f};
  __syncthreads();

  for (int s = 0; s < 256; ++s) {
    const unsigned tag = (unsigned)(s + 1);
    const unsigned base = ((unsigned)(s & 1) * 8 + (unsigned)g) * 8192;
    // prefetch elementwise inputs (overlap with MFMA)
    f32x4 fct = *(const f32x4*)(fptr + (size_t)s * 512);
    float gval = gptr[s];
    // ---- matvec: wave computes its 2 n-tiles over 16 ktiles ----
    f32x4 acc0 = (f32x4){0.f, 0.f, 0.f, 0.f};
    f32x4 acc1 = (f32x4){0.f, 0.f, 0.f, 0.f};
#pragma unroll
    for (int kt = 0; kt < 16; ++kt) {
      i32x4 av = *(const i32x4*)&A[lm * 520 + kt * 32 + lk * 8];
      bf16x8 afv = __builtin_bit_cast(bf16x8, av);
      acc0 = __builtin_amdgcn_mfma_f32_16x16x32_bf16(
          afv, __builtin_bit_cast(bf16x8, bfr[0][kt]), acc0, 0, 0, 0);
      acc1 = __builtin_amdgcn_mfma_f32_16x16x32_bf16(
          afv, __builtin_bit_cast(bf16x8, bfr[1][kt]), acc1, 0, 0, 0);
    }
#pragma unroll
    for (int r = 0; r < 4; ++r) {
      outb[ot * 272 + (lk * 4 + r) * 17 + lm] = acc0[r];
      outb[(ot + 1) * 272 + (lk * 4 + r) * 17 + lm] = acc1[r];
    }
    __syncthreads();  // outb ready; A's step-s MFMA reads complete
    // ---- elementwise update + tagged publish (all 512 threads) ----
    {
      unsigned short pk[4];
#pragma unroll
      for (int r = 0; r < 4; ++r) {
        const int n_loc = nl0 + r;
        const float uro = outb[(n_loc >> 4) * 272 + bb * 17 + (n_loc & 15)];
        const float uuo =
            outb[(8 + (n_loc >> 4)) * 272 + bb * 17 + (n_loc & 15)];
        const float pr = fct[r] * c_rsr[r] + c_br[r];
        const float ph = fct[r] * c_rsh[r] + c_bw[r];
        const float r_ = fast_sigmoid(pr + uro + c_bur[r]);
        const float ht = fast_tanh(ph + r_ * (uuo + c_bu[r]));
        Cv[r] = gval * ht + (1.0f - gval) * Cv[r];
        pk[r] = f2bf(Cv[r]);
      }
      // publish: 4 self-tagged dwords as 2 u64 agent stores (fabric ASAP)
      const u64 q0 = (u64)(((unsigned)pk[0] << 16) | tag) |
                     ((u64)(((unsigned)pk[1] << 16) | tag) << 32);
      const u64 q1 = (u64)(((unsigned)pk[2] << 16) | tag) |
                     ((u64)(((unsigned)pk[3] << 16) | tag) << 32);
      u64* dst = (u64*)(EX + base + (unsigned)bb * 512 + (unsigned)n0);
      __hip_atomic_store(dst, q0, __ATOMIC_RELAXED, __HIP_MEMORY_SCOPE_AGENT);
      __hip_atomic_store(dst + 1, q1, __ATOMIC_RELAXED, __HIP_MEMORY_SCOPE_AGENT);
      // own slice straight into A-LDS
      const u64 word = (u64)pk[0] | ((u64)pk[1] << 16) | ((u64)pk[2] << 32) |
                       ((u64)pk[3] << 48);
      *(u64*)((char*)A + bb * 1040 + n0 * 2) = word;
    }
    // ---- self-tagged gather: column-pair cu, rows rbase,rbase+2,..,rbase+14
    if (!ownCol) {
      const u64* srcq = (const u64*)(EX + base) + (unsigned)cu;
      unsigned short* dA = (unsigned short*)((char*)A + cu * 4);
      u64 vbuf[8];
#pragma unroll
      for (int i = 0; i < 8; ++i)
        vbuf[i] = __hip_atomic_load(srcq + (i * 2 + rbase) * 256,
                                    __ATOMIC_RELAXED, __HIP_MEMORY_SCOPE_AGENT);
      unsigned pending = 0;
#pragma unroll
      for (int i = 0; i < 8; ++i) {
        const u64 v = vbuf[i];
        if ((v & 0xFFFFu) == tag && ((v >> 32) & 0xFFFFu) == tag) {
          const unsigned pk2 =
              (unsigned)((v >> 16) & 0xFFFFu) | ((unsigned)(v >> 48) << 16);
          *(unsigned*)((char*)dA + (i * 2 + rbase) * 1040) = pk2;
        } else {
          pending |= 1u << i;
        }
      }
      int guard = 0;
      while (pending) {
        __builtin_amdgcn_s_sleep(2);  // 128-cyc backoff: no fabric hammering
        unsigned np = pending;
#pragma unroll
        for (int i = 0; i < 8; ++i) {
          if ((np >> i) & 1u) {
            const u64 v = __hip_atomic_load(srcq + (i * 2 + rbase) * 256,
                                            __ATOMIC_RELAXED,
                                            __HIP_MEMORY_SCOPE_AGENT);
            if ((v & 0xFFFFu) == tag && ((v >> 32) & 0xFFFFu) == tag) {
              const unsigned pk2 =
                  (unsigned)((v >> 16) & 0xFFFFu) | ((unsigned)(v >> 48) << 16);
              *(unsigned*)((char*)dA + (i * 2 + rbase) * 1040) = pk2;
              np &= ~(1u << i);
            }
          }
        }
        pending = np;
        if (++guard > (1 << 16)) break;  // hang-safety bailout
      }
    }
    __syncthreads();  // A fully assembled for next step
  }
  *(f32x4*)(Cb + (size_t)batch * 512 + n0) = Cv;
}

// ---------------------------------------------------------------------------
// Final: out[b] = relu([prevM | C | questions] @ nm_w + nm_b). 2 batches/WG.
// ---------------------------------------------------------------------------
__global__ __launch_bounds__(512) void k_final(
    const float* __restrict__ prevM, const float* __restrict__ questions,
    const float* __restrict__ Cb, const float* __restrict__ nmw,
    const float* __restrict__ nmb, float* __restrict__ out) {
  __shared__ float cc[2][1536];
  const int t = threadIdx.x;
  const int b0 = blockIdx.x * 2;
  for (int i = t; i < 1536; i += 512) {
#pragma unroll
    for (int bi = 0; bi < 2; ++bi) {
      int bbx = b0 + bi;
      float v;
      if (i < 512) v = prevM[bbx * 512 + i];
      else if (i < 1024) v = Cb[bbx * 512 + i - 512];
      else v = questions[bbx * 512 + i - 1024];
      cc[bi][i] = v;
    }
  }
  __syncthreads();
  const int h = t;
  float a0 = nmb[h], a1 = nmb[h];
#pragma unroll 4
  for (int f = 0; f < 1536; ++f) {
    float wv = nmw[f * 512 + h];
    a0 = fmaf(cc[0][f], wv, a0);
    a1 = fmaf(cc[1][f], wv, a1);
  }
  out[(size_t)b0 * 512 + h] = fmaxf(a0, 0.f);
  out[(size_t)(b0 + 1) * 512 + h] = fmaxf(a1, 0.f);
}

// ---------------------------------------------------------------------------
extern "C" void kernel_launch(void* const* d_in, const int* in_sizes, int n_in,
                              void* d_out, int out_size, void* d_ws,
                              size_t ws_size, hipStream_t stream) {
  const float* facts     = (const float*)d_in[0];
  const float* questions = (const float*)d_in[1];
  const float* prevM     = (const float*)d_in[2];
  const float* z1w       = (const float*)d_in[3];
  const float* z1b       = (const float*)d_in[4];
  const float* z2w       = (const float*)d_in[5];
  // d_in[6] = z2_b: softmax shift-invariant, unused (exact)
  const float* Wr        = (const float*)d_in[7];
  const float* br        = (const float*)d_in[8];
  const float* Ur        = (const float*)d_in[9];
  const float* bur       = (const float*)d_in[10];
  const float* W         = (const float*)d_in[11];
  const float* bw        = (const float*)d_in[12];
  const float* U         = (const float*)d_in[13];
  const float* bu        = (const float*)d_in[14];
  const float* nmw       = (const float*)d_in[15];
  const float* nmb       = (const float*)d_in[16];

  char* ws = (char*)d_ws;
  float* G             = (float*)(ws + OFF_G);
  float* rsr           = (float*)(ws + OFF_RSR);
  float* rsh           = (float*)(ws + OFF_RSH);
  unsigned* EX         = (unsigned*)(ws + OFF_EX);
  float* Cb            = (float*)(ws + OFF_CBUF);
  float* logits        = (float*)(ws + OFF_LOGITS);
  unsigned short* Bp   = (unsigned short*)(ws + OFF_BP);
  unsigned short* PB   = (unsigned short*)(ws + OFF_PB);

  k_prep_bp<<<2048, 512, 0, stream>>>(z1w, Bp);
  k_prep_pb<<<1024, 512, 0, stream>>>(Ur, U, PB);
  k_prep_rs<<<1024, 256, 0, stream>>>(Wr, W, rsr, rsh);
  k_gate<<<512, 512, 0, stream>>>(facts, questions, prevM, z1b, z2w, Bp, logits);
  k_softmax<<<128, 256, 0, stream>>>(logits, G);
  k_scan<<<32, 512, 0, stream>>>(facts, G, PB, rsr, rsh, br, bur, bw, bu, EX, Cb);
  k_final<<<64, 512, 0, stream>>>(prevM, questions, Cb, nmw, nmb, (float*)d_out);
}

// Round 6
// 1139.644 us; speedup vs baseline: 1.4069x; 1.2332x over previous
//
#include <hip/hip_runtime.h>
#include <stdint.h>

// Problem constants: B=128, S=256, H=512
#define B_ 128
#define S_ 256
#define H_ 512

typedef __attribute__((ext_vector_type(4))) float f32x4;
typedef __attribute__((ext_vector_type(4))) int i32x4;
typedef __attribute__((ext_vector_type(2))) unsigned int u32x2;
typedef __attribute__((ext_vector_type(8))) __bf16 bf16x8;
typedef unsigned long long u64;

// ---------- workspace layout (bytes) ----------
#define OFF_G      0          // 32768 f32 = 131072 B
#define OFF_RSR    131072     // 512 f32
#define OFF_RSH    133120     // 512 f32
#define OFF_FLG    135168     // 32 u32 flags (+pad to 4 KiB)
#define OFF_EX     139264     // 2 parity x 8 groups x 16 rows x 256 dw = 262144 B
#define OFF_CBUF   401408     // 128 x 512 f32 = 262144 B
#define OFF_BP     663552     // z1_w packed bf16 = 2097152 B
#define OFF_PB     2760704    // scan weights packed bf16 = 1048576 B
#define OFF_LOGITS 3809280    // 32768 f32 = 131072 B
// total ~3.94 MB

__device__ __forceinline__ unsigned short f2bf(float f) {
  unsigned u = __builtin_bit_cast(unsigned, f);
  u += 0x7FFFu + ((u >> 16) & 1u);
  return (unsigned short)(u >> 16);
}
__device__ __forceinline__ float fast_sigmoid(float x) {
  return 1.0f / (1.0f + __expf(-x));
}
__device__ __forceinline__ float fast_tanh(float x) {
  return 1.0f - 2.0f / (__expf(2.0f * x) + 1.0f);
}

// ---------------------------------------------------------------------------
// Prep 1: pack z1_w (2048x512 f32) -> bf16, layout Bp[(k>>3)*512+n][k&7]
// ---------------------------------------------------------------------------
__global__ void k_prep_bp(const float* __restrict__ z1w,
                          unsigned short* __restrict__ Bp) {
  int t = blockIdx.x * blockDim.x + threadIdx.x;  // < 2048*512
  int k = t >> 9, n = t & 511;
  Bp[((k >> 3) * 512 + n) * 8 + (k & 7)] = f2bf(z1w[t]);
}

// ---------------------------------------------------------------------------
// Prep 2: pack Ur,U into per-(mem 0..3, wave 0..7, jn 0..1, ktile, lane) MFMA
// B-fragments. mat = w>>2 (0=Ur,1=U); n = mem*128 + ((w&3)*2+jn)*16 + (l&15).
// ---------------------------------------------------------------------------
__global__ void k_prep_pb(const float* __restrict__ Ur,
                          const float* __restrict__ U,
                          unsigned short* __restrict__ PB) {
  int t = blockIdx.x * blockDim.x + threadIdx.x;  // < 524288
  int j = t & 7;
  int l = (t >> 3) & 63;
  int kt = (t >> 9) & 15;
  int jn = (t >> 13) & 1;
  int w = (t >> 14) & 7;
  int mem = t >> 17;  // 0..3
  int k = kt * 32 + ((l >> 4) & 3) * 8 + j;
  int n = mem * 128 + ((w & 3) * 2 + jn) * 16 + (l & 15);
  const float* src = (w >> 2) ? U : Ur;
  PB[t] = f2bf(src[k * 512 + n]);
}

// ---------------------------------------------------------------------------
// Prep 3: row sums of Wr and W ('bsh,hk->bsh' collapses to these)
// ---------------------------------------------------------------------------
__global__ void k_prep_rs(const float* __restrict__ Wr,
                          const float* __restrict__ W,
                          float* __restrict__ rsr, float* __restrict__ rsh) {
  __shared__ float red[4];
  int h2 = blockIdx.x;
  int t = threadIdx.x;
  const float* M = (h2 >= 512) ? W : Wr;
  int h = h2 & 511;
  float sv = M[h * 512 + t] + M[h * 512 + 256 + t];
#pragma unroll
  for (int mask = 1; mask < 64; mask <<= 1) sv += __shfl_xor(sv, mask, 64);
  if ((t & 63) == 0) red[t >> 6] = sv;
  __syncthreads();
  if (t == 0) {
    float tot = red[0] + red[1] + red[2] + red[3];
    ((h2 >= 512) ? rsh : rsr)[h] = tot;
  }
}

// ---------------------------------------------------------------------------
// Gate GEMM + fused tanh/dot epilogue.
// NEW: B-staging via global_load_lds width=16 (async DMA, no VGPR roundtrip).
// Wave w stages its 4 KB chunk: lds dest is wave-uniform base + lane*16 —
// exactly the instruction's addressing model.
// ---------------------------------------------------------------------------
__global__ __launch_bounds__(512, 4) void k_gate(
    const float* __restrict__ facts, const float* __restrict__ questions,
    const float* __restrict__ prevM, const float* __restrict__ z1b,
    const float* __restrict__ z2w, const unsigned short* __restrict__ Bp,
    float* __restrict__ logits) {
  __shared__ float qS[512], mS[512], z1bS[512], z2wS[512];
  __shared__ unsigned short At[64 * 40];
  __shared__ unsigned short Bt[16384];
  __shared__ float lp[64 * 4];
  const int tid = threadIdx.x;
  const int row0 = blockIdx.x * 64;
  const int b = row0 >> 8;
  const int s0 = row0 & 255;
  qS[tid] = questions[b * 512 + tid];
  mS[tid] = prevM[b * 512 + tid];
  z1bS[tid] = z1b[tid];
  z2wS[tid] = z2w[tid];
  const int w = tid >> 6, l = tid & 63;
  const int mgrp = w & 1, ngrp = w >> 1;
  const int lm = l & 15, lk = l >> 4;
  f32x4 acc[2][8];
#pragma unroll
  for (int a = 0; a < 2; ++a)
#pragma unroll
    for (int i = 0; i < 8; ++i) acc[a][i] = (f32x4){0.f, 0.f, 0.f, 0.f};
  const int arow = tid >> 3, ac = tid & 7;
  const float* fbase = facts + ((size_t)(b * 256 + s0 + arow)) * 512 + ac * 4;

  for (int kb = 0; kb < 64; ++kb) {
    __syncthreads();
    // ---- async-stage B tile: 32 KB via 4 DMA instrs per wave ----
    {
      const char* gsrc = (const char*)Bp + (size_t)kb * 32768 + w * 4096 + l * 16;
#pragma unroll
      for (int i = 0; i < 4; ++i)
        __builtin_amdgcn_global_load_lds(
            (const __attribute__((address_space(1))) unsigned int*)(gsrc +
                                                                    i * 1024),
            (__attribute__((address_space(3))) unsigned int*)((char*)Bt +
                                                              w * 4096 +
                                                              i * 1024),
            16, 0, 0);
    }
    // ---- build A tile (64 rows x 32 k) in bf16 (overlaps DMA) ----
    const int part = kb >> 4;          // 0: f*q, 1: f*m, 2: |f-q|, 3: |f-m|
    const int h0 = (kb & 15) * 32;
    f32x4 fv = *(const f32x4*)(fbase + h0);
    f32x4 ov = (part & 1) ? *(const f32x4*)&mS[h0 + ac * 4]
                          : *(const f32x4*)&qS[h0 + ac * 4];
    float z0, z1, z2, z3;
    if (part < 2) {
      z0 = fv[0] * ov[0]; z1 = fv[1] * ov[1];
      z2 = fv[2] * ov[2]; z3 = fv[3] * ov[3];
    } else {
      z0 = fabsf(fv[0] - ov[0]); z1 = fabsf(fv[1] - ov[1]);
      z2 = fabsf(fv[2] - ov[2]); z3 = fabsf(fv[3] - ov[3]);
    }
    unsigned p0 = (unsigned)f2bf(z0) | ((unsigned)f2bf(z1) << 16);
    unsigned p1 = (unsigned)f2bf(z2) | ((unsigned)f2bf(z3) << 16);
    u32x2 pk = {p0, p1};
    *(u32x2*)&At[arow * 40 + ac * 4] = pk;
    __syncthreads();  // barrier drains DMA (vmcnt) + A-writes (lgkmcnt)
    // ---- fragments + MFMA ----
    bf16x8 af[2];
#pragma unroll
    for (int mi = 0; mi < 2; ++mi) {
      i32x4 av = *(const i32x4*)&At[((mgrp * 2 + mi) * 16 + lm) * 40 + lk * 8];
      af[mi] = __builtin_bit_cast(bf16x8, av);
    }
#pragma unroll
    for (int i = 0; i < 8; ++i) {
      const int nt = ngrp * 8 + i;
      i32x4 bv = *(const i32x4*)&Bt[lk * 4096 + (nt * 16 + lm) * 8];
      bf16x8 bf = __builtin_bit_cast(bf16x8, bv);
      acc[0][i] = __builtin_amdgcn_mfma_f32_16x16x32_bf16(af[0], bf, acc[0][i], 0, 0, 0);
      acc[1][i] = __builtin_amdgcn_mfma_f32_16x16x32_bf16(af[1], bf, acc[1][i], 0, 0, 0);
    }
  }
  float pr_[2][4];
#pragma unroll
  for (int mi = 0; mi < 2; ++mi)
#pragma unroll
    for (int r = 0; r < 4; ++r) pr_[mi][r] = 0.f;
#pragma unroll
  for (int i = 0; i < 8; ++i) {
    const int n_i = (ngrp * 8 + i) * 16 + lm;
    const float zb = z1bS[n_i], zw = z2wS[n_i];
#pragma unroll
    for (int mi = 0; mi < 2; ++mi)
#pragma unroll
      for (int r = 0; r < 4; ++r)
        pr_[mi][r] += fast_tanh(acc[mi][i][r] + zb) * zw;
  }
#pragma unroll
  for (int mask = 1; mask < 16; mask <<= 1)
#pragma unroll
    for (int mi = 0; mi < 2; ++mi)
#pragma unroll
      for (int r = 0; r < 4; ++r)
        pr_[mi][r] += __shfl_xor(pr_[mi][r], mask, 64);
  if (lm == 0) {
#pragma unroll
    for (int mi = 0; mi < 2; ++mi)
#pragma unroll
      for (int r = 0; r < 4; ++r)
        lp[((mgrp * 2 + mi) * 16 + lk * 4 + r) * 4 + ngrp] = pr_[mi][r];
  }
  __syncthreads();
  if (tid < 64)
    logits[row0 + tid] =
        lp[tid * 4] + lp[tid * 4 + 1] + lp[tid * 4 + 2] + lp[tid * 4 + 3];
}

// ---------------------------------------------------------------------------
// Softmax over S per batch (z2_b dropped: shift-invariant, exact)
// ---------------------------------------------------------------------------
__global__ void k_softmax(const float* __restrict__ logits,
                          float* __restrict__ G) {
  __shared__ float red[4], red2[4];
  int b = blockIdx.x, t = threadIdx.x;
  float v = logits[b * 256 + t];
  float mx = v;
#pragma unroll
  for (int mask = 1; mask < 64; mask <<= 1)
    mx = fmaxf(mx, __shfl_xor(mx, mask, 64));
  if ((t & 63) == 0) red[t >> 6] = mx;
  __syncthreads();
  mx = fmaxf(fmaxf(red[0], red[1]), fmaxf(red[2], red[3]));
  float e = __expf(v - mx);
  float sm = e;
#pragma unroll
  for (int mask = 1; mask < 64; mask <<= 1) sm += __shfl_xor(sm, mask, 64);
  if ((t & 63) == 0) red2[t >> 6] = sm;
  __syncthreads();
  sm = red2[0] + red2[1] + red2[2] + red2[3];
  G[b * 256 + t] = e / sm;
}

// ---------------------------------------------------------------------------
// Scan v6: R3's proven flag+gather protocol on the 4-member grouping.
// 8 groups x 4 member-WGs (32 WGs), 16 batches/group, N=128/WG, weights
// VGPR-resident. Per step: MFMA -> elementwise -> untagged 8B data stores
// -> __syncthreads (vmcnt drain) -> 1 flag store -> 3 lanes poll 3 remote
// flags (s_sleep backoff) -> one-shot coalesced gather. Readiness detection
// concentrated on one flag line; bulk data moved exactly once (R4/R5's
// self-tagged polling wasted full-volume RTs pre-arrival). Parity
// double-buffered; flags monotone (memset 0 per launch).
// ---------------------------------------------------------------------------
__global__ __launch_bounds__(512, 1) void k_scan(
    const float* __restrict__ facts, const float* __restrict__ Gm,
    const unsigned short* __restrict__ PB, const float* __restrict__ rsr,
    const float* __restrict__ rsh, const float* __restrict__ br,
    const float* __restrict__ bur, const float* __restrict__ bw,
    const float* __restrict__ bu, u64* __restrict__ EXq,
    unsigned int* __restrict__ FLG, float* __restrict__ Cb) {
  __shared__ unsigned short A[16 * 520];  // 16 rows x 512 bf16, 1040B pitch
  __shared__ float outb[16 * 272];        // [tile16][row16 pitch17]
  const int tid = threadIdx.x;
  const int g = blockIdx.x & 7;    // group (same XCD under %8 round-robin)
  const int mem = blockIdx.x >> 3; // member 0..3, n-slice [mem*128, +128)
  const int w = tid >> 6, l = tid & 63;
  const int lm = l & 15, lk = (l >> 4) & 3;
  // zero A
  for (int i = tid; i < 16 * 520 / 4; i += 512) ((u64*)A)[i] = 0ull;
  // weight fragments resident in VGPRs: wave w = (mat = w>>2, ntile-pair w&3)
  i32x4 bfr[2][16];
  const char* pb = (const char*)PB + (size_t)(mem * 8 + w) * 32768;
#pragma unroll
  for (int jn = 0; jn < 2; ++jn)
#pragma unroll
    for (int kt = 0; kt < 16; ++kt)
      bfr[jn][kt] = *(const i32x4*)(pb + (jn * 16 + kt) * 1024 + l * 16);
  const int ot = (w >> 2) * 8 + (w & 3) * 2;  // outb tile base for this wave
  // producer lane: thread owns (bb, 4 consecutive n)
  const int bb = tid >> 5;           // 0..15
  const int nqq = tid & 31;          // n-quad within slice
  const int n0 = mem * 128 + nqq * 4;
  const int nl0 = nqq * 4;           // n_loc base within slice
  const int batch = g * 16 + bb;
  const f32x4 c_rsr = *(const f32x4*)(rsr + n0);
  const f32x4 c_br  = *(const f32x4*)(br + n0);
  const f32x4 c_rsh = *(const f32x4*)(rsh + n0);
  const f32x4 c_bw  = *(const f32x4*)(bw + n0);
  const f32x4 c_bur = *(const f32x4*)(bur + n0);
  const f32x4 c_bu  = *(const f32x4*)(bu + n0);
  const float* fptr = facts + (size_t)batch * 256 * 512 + n0;
  const float* gptr = Gm + batch * 256;
  // gather mapping: thread covers (row = tid>>5, u64-unit cu = tid&31) in
  // each remote quadrant q (32 u64-units of 4 n per 16-row block)
  const int grow = tid >> 5, gcu = tid & 31;
  const int pollmem = (tid < mem) ? tid : tid + 1;  // lanes 0..2 -> 3 remotes
  f32x4 Cv = (f32x4){0.f, 0.f, 0.f, 0.f};
  __syncthreads();

  for (int s = 0; s < 256; ++s) {
    const unsigned tag = (unsigned)(s + 1);
    const unsigned rbase = ((unsigned)(s & 1) * 8 + (unsigned)g) * 16;  // rows
    // prefetch elementwise inputs (overlap with MFMA)
    f32x4 fct = *(const f32x4*)(fptr + (size_t)s * 512);
    float gval = gptr[s];
    // ---- matvec: wave computes its 2 n-tiles over 16 ktiles ----
    f32x4 acc0 = (f32x4){0.f, 0.f, 0.f, 0.f};
    f32x4 acc1 = (f32x4){0.f, 0.f, 0.f, 0.f};
#pragma unroll
    for (int kt = 0; kt < 16; ++kt) {
      i32x4 av = *(const i32x4*)&A[lm * 520 + kt * 32 + lk * 8];
      bf16x8 afv = __builtin_bit_cast(bf16x8, av);
      acc0 = __builtin_amdgcn_mfma_f32_16x16x32_bf16(
          afv, __builtin_bit_cast(bf16x8, bfr[0][kt]), acc0, 0, 0, 0);
      acc1 = __builtin_amdgcn_mfma_f32_16x16x32_bf16(
          afv, __builtin_bit_cast(bf16x8, bfr[1][kt]), acc1, 0, 0, 0);
    }
#pragma unroll
    for (int r = 0; r < 4; ++r) {
      outb[ot * 272 + (lk * 4 + r) * 17 + lm] = acc0[r];
      outb[(ot + 1) * 272 + (lk * 4 + r) * 17 + lm] = acc1[r];
    }
    __syncthreads();  // outb ready; A's step-s MFMA reads complete
    // ---- elementwise update + untagged publish ----
    {
      unsigned short pk[4];
#pragma unroll
      for (int r = 0; r < 4; ++r) {
        const int n_loc = nl0 + r;
        const float uro = outb[(n_loc >> 4) * 272 + bb * 17 + (n_loc & 15)];
        const float uuo =
            outb[(8 + (n_loc >> 4)) * 272 + bb * 17 + (n_loc & 15)];
        const float pr = fct[r] * c_rsr[r] + c_br[r];
        const float ph = fct[r] * c_rsh[r] + c_bw[r];
        const float r_ = fast_sigmoid(pr + uro + c_bur[r]);
        const float ht = fast_tanh(ph + r_ * (uuo + c_bu[r]));
        Cv[r] = gval * ht + (1.0f - gval) * Cv[r];
        pk[r] = f2bf(Cv[r]);
      }
      const u64 word = (u64)pk[0] | ((u64)pk[1] << 16) | ((u64)pk[2] << 32) |
                       ((u64)pk[3] << 48);
      // publish 8B for the 3 remote members
      __hip_atomic_store(EXq + (rbase + (unsigned)bb) * 128 + (unsigned)(n0 >> 2),
                         word, __ATOMIC_RELAXED, __HIP_MEMORY_SCOPE_AGENT);
      // own slice straight into A-LDS
      *(u64*)((char*)A + bb * 1040 + n0 * 2) = word;
    }
    __syncthreads();  // per-thread vmcnt(0): all data stores drained
    if (tid == 0)
      __hip_atomic_store(FLG + g * 4 + mem, tag, __ATOMIC_RELAXED,
                         __HIP_MEMORY_SCOPE_AGENT);
    // ---- poll 3 remote flags (lanes 0..2 of wave 0) with backoff ----
    if (tid < 3) {
      int guard = 0;
      for (;;) {
        unsigned v = __hip_atomic_load(FLG + g * 4 + pollmem, __ATOMIC_RELAXED,
                                       __HIP_MEMORY_SCOPE_AGENT);
        if (v >= tag) break;
        __builtin_amdgcn_s_sleep(1);
        if (++guard > (1 << 22)) break;  // hang-safety bailout
      }
    }
    __syncthreads();  // all 3 remote slices published & visible
    // ---- one-shot gather: 3 coalesced 8B loads per thread ----
#pragma unroll
    for (int q = 0; q < 4; ++q) {
      if (q != mem) {
        u64 wv = __hip_atomic_load(
            EXq + (rbase + (unsigned)grow) * 128 + (unsigned)(q * 32 + gcu),
            __ATOMIC_RELAXED, __HIP_MEMORY_SCOPE_AGENT);
        *(u64*)((char*)A + grow * 1040 + q * 256 + gcu * 8) = wv;
      }
    }
    __syncthreads();  // A fully assembled for next step
  }
  *(f32x4*)(Cb + (size_t)batch * 512 + n0) = Cv;
}

// ---------------------------------------------------------------------------
// Final: out[b] = relu([prevM | C | questions] @ nm_w + nm_b). 2 batches/WG.
// ---------------------------------------------------------------------------
__global__ __launch_bounds__(512) void k_final(
    const float* __restrict__ prevM, const float* __restrict__ questions,
    const float* __restrict__ Cb, const float* __restrict__ nmw,
    const float* __restrict__ nmb, float* __restrict__ out) {
  __shared__ float cc[2][1536];
  const int t = threadIdx.x;
  const int b0 = blockIdx.x * 2;
  for (int i = t; i < 1536; i += 512) {
#pragma unroll
    for (int bi = 0; bi < 2; ++bi) {
      int bbx = b0 + bi;
      float v;
      if (i < 512) v = prevM[bbx * 512 + i];
      else if (i < 1024) v = Cb[bbx * 512 + i - 512];
      else v = questions[bbx * 512 + i - 1024];
      cc[bi][i] = v;
    }
  }
  __syncthreads();
  const int h = t;
  float a0 = nmb[h], a1 = nmb[h];
#pragma unroll 4
  for (int f = 0; f < 1536; ++f) {
    float wv = nmw[f * 512 + h];
    a0 = fmaf(cc[0][f], wv, a0);
    a1 = fmaf(cc[1][f], wv, a1);
  }
  out[(size_t)b0 * 512 + h] = fmaxf(a0, 0.f);
  out[(size_t)(b0 + 1) * 512 + h] = fmaxf(a1, 0.f);
}

// ---------------------------------------------------------------------------
extern "C" void kernel_launch(void* const* d_in, const int* in_sizes, int n_in,
                              void* d_out, int out_size, void* d_ws,
                              size_t ws_size, hipStream_t stream) {
  const float* facts     = (const float*)d_in[0];
  const float* questions = (const float*)d_in[1];
  const float* prevM     = (const float*)d_in[2];
  const float* z1w       = (const float*)d_in[3];
  const float* z1b       = (const float*)d_in[4];
  const float* z2w       = (const float*)d_in[5];
  // d_in[6] = z2_b: softmax shift-invariant, unused (exact)
  const float* Wr        = (const float*)d_in[7];
  const float* br        = (const float*)d_in[8];
  const float* Ur        = (const float*)d_in[9];
  const float* bur       = (const float*)d_in[10];
  const float* W         = (const float*)d_in[11];
  const float* bw        = (const float*)d_in[12];
  const float* U         = (const float*)d_in[13];
  const float* bu        = (const float*)d_in[14];
  const float* nmw       = (const float*)d_in[15];
  const float* nmb       = (const float*)d_in[16];

  char* ws = (char*)d_ws;
  float* G             = (float*)(ws + OFF_G);
  float* rsr           = (float*)(ws + OFF_RSR);
  float* rsh           = (float*)(ws + OFF_RSH);
  unsigned* FLG        = (unsigned*)(ws + OFF_FLG);
  u64* EXq             = (u64*)(ws + OFF_EX);
  float* Cb            = (float*)(ws + OFF_CBUF);
  float* logits        = (float*)(ws + OFF_LOGITS);
  unsigned short* Bp   = (unsigned short*)(ws + OFF_BP);
  unsigned short* PB   = (unsigned short*)(ws + OFF_PB);

  hipMemsetAsync(FLG, 0, 32 * sizeof(unsigned), stream);
  k_prep_bp<<<2048, 512, 0, stream>>>(z1w, Bp);
  k_prep_pb<<<1024, 512, 0, stream>>>(Ur, U, PB);
  k_prep_rs<<<1024, 256, 0, stream>>>(Wr, W, rsr, rsh);
  k_gate<<<512, 512, 0, stream>>>(facts, questions, prevM, z1b, z2w, Bp, logits);
  k_softmax<<<128, 256, 0, stream>>>(logits, G);
  k_scan<<<32, 512, 0, stream>>>(facts, G, PB, rsr, rsh, br, bur, bw, bu, EXq,
                                 FLG, Cb);
  k_final<<<64, 512, 0, stream>>>(prevM, questions, Cb, nmw, nmb, (float*)d_out);
}

// Round 7
// 1121.230 us; speedup vs baseline: 1.4300x; 1.0164x over previous
//
#include <hip/hip_runtime.h>
#include <stdint.h>

// Problem constants: B=128, S=256, H=512
#define B_ 128
#define S_ 256
#define H_ 512

typedef __attribute__((ext_vector_type(4))) float f32x4;
typedef __attribute__((ext_vector_type(4))) int i32x4;
typedef __attribute__((ext_vector_type(2))) unsigned int u32x2;
typedef __attribute__((ext_vector_type(8))) __bf16 bf16x8;
typedef unsigned long long u64;

// ---------- workspace layout (bytes) ----------
#define OFF_G      0          // G transposed [s][b]: 32768 f32 = 131072 B
#define OFF_RSR    131072     // 512 f32
#define OFF_RSH    133120     // 512 f32
#define OFF_FLG    135168     // 32 u32 flags (+pad to 4 KiB)
#define OFF_EX     139264     // 2 parity x 8 groups x 16 rows x 256 dw = 262144 B
#define OFF_CBUF   401408     // 128 x 512 f32 = 262144 B
#define OFF_BP     663552     // z1_w packed bf16 = 2097152 B
#define OFF_PB     2760704    // scan weights packed bf16 = 1048576 B
#define OFF_LOGITS 3809280    // 32768 f32 = 131072 B
// total ~3.94 MB

__device__ __forceinline__ unsigned short f2bf(float f) {
  unsigned u = __builtin_bit_cast(unsigned, f);
  u += 0x7FFFu + ((u >> 16) & 1u);
  return (unsigned short)(u >> 16);
}
__device__ __forceinline__ float fast_sigmoid(float x) {
  return 1.0f / (1.0f + __expf(-x));
}
__device__ __forceinline__ float fast_tanh(float x) {
  return 1.0f - 2.0f / (__expf(2.0f * x) + 1.0f);
}

// ---------------------------------------------------------------------------
// Prep 1: pack z1_w (2048x512 f32) -> bf16, layout Bp[(k>>3)*512+n][k&7]
// ---------------------------------------------------------------------------
__global__ void k_prep_bp(const float* __restrict__ z1w,
                          unsigned short* __restrict__ Bp) {
  int t = blockIdx.x * blockDim.x + threadIdx.x;  // < 2048*512
  int k = t >> 9, n = t & 511;
  Bp[((k >> 3) * 512 + n) * 8 + (k & 7)] = f2bf(z1w[t]);
}

// ---------------------------------------------------------------------------
// Prep 2: pack Ur,U as MFMA B-fragments, NEW v7 layout:
// wave w owns ntile w for BOTH matrices.
// index: (((mem*8 + w)*2 + mat)*16 + kt)*64*8 + l*8 + j
// k = kt*32 + ((l>>4)&3)*8 + j ; n = mem*128 + w*16 + (l&15)
// ---------------------------------------------------------------------------
__global__ void k_prep_pb(const float* __restrict__ Ur,
                          const float* __restrict__ U,
                          unsigned short* __restrict__ PB) {
  int t = blockIdx.x * blockDim.x + threadIdx.x;  // < 524288
  int j = t & 7;
  int l = (t >> 3) & 63;
  int kt = (t >> 9) & 15;
  int mat = (t >> 13) & 1;
  int w = (t >> 14) & 7;
  int mem = t >> 17;  // 0..3
  int k = kt * 32 + ((l >> 4) & 3) * 8 + j;
  int n = mem * 128 + w * 16 + (l & 15);
  const float* src = mat ? U : Ur;
  PB[t] = f2bf(src[k * 512 + n]);
}

// ---------------------------------------------------------------------------
// Prep 3: row sums of Wr and W ('bsh,hk->bsh' collapses to these)
// ---------------------------------------------------------------------------
__global__ void k_prep_rs(const float* __restrict__ Wr,
                          const float* __restrict__ W,
                          float* __restrict__ rsr, float* __restrict__ rsh) {
  __shared__ float red[4];
  int h2 = blockIdx.x;
  int t = threadIdx.x;
  const float* M = (h2 >= 512) ? W : Wr;
  int h = h2 & 511;
  float sv = M[h * 512 + t] + M[h * 512 + 256 + t];
#pragma unroll
  for (int mask = 1; mask < 64; mask <<= 1) sv += __shfl_xor(sv, mask, 64);
  if ((t & 63) == 0) red[t >> 6] = sv;
  __syncthreads();
  if (t == 0) {
    float tot = red[0] + red[1] + red[2] + red[3];
    ((h2 >= 512) ? rsh : rsr)[h] = tot;
  }
}

// ---------------------------------------------------------------------------
// Gate GEMM + fused tanh/dot epilogue (unchanged from R6)
// ---------------------------------------------------------------------------
__global__ __launch_bounds__(512, 4) void k_gate(
    const float* __restrict__ facts, const float* __restrict__ questions,
    const float* __restrict__ prevM, const float* __restrict__ z1b,
    const float* __restrict__ z2w, const unsigned short* __restrict__ Bp,
    float* __restrict__ logits) {
  __shared__ float qS[512], mS[512], z1bS[512], z2wS[512];
  __shared__ unsigned short At[64 * 40];
  __shared__ unsigned short Bt[16384];
  __shared__ float lp[64 * 4];
  const int tid = threadIdx.x;
  const int row0 = blockIdx.x * 64;
  const int b = row0 >> 8;
  const int s0 = row0 & 255;
  qS[tid] = questions[b * 512 + tid];
  mS[tid] = prevM[b * 512 + tid];
  z1bS[tid] = z1b[tid];
  z2wS[tid] = z2w[tid];
  const int w = tid >> 6, l = tid & 63;
  const int mgrp = w & 1, ngrp = w >> 1;
  const int lm = l & 15, lk = l >> 4;
  f32x4 acc[2][8];
#pragma unroll
  for (int a = 0; a < 2; ++a)
#pragma unroll
    for (int i = 0; i < 8; ++i) acc[a][i] = (f32x4){0.f, 0.f, 0.f, 0.f};
  const int arow = tid >> 3, ac = tid & 7;
  const float* fbase = facts + ((size_t)(b * 256 + s0 + arow)) * 512 + ac * 4;

  for (int kb = 0; kb < 64; ++kb) {
    __syncthreads();
    {
      const char* gsrc = (const char*)Bp + (size_t)kb * 32768 + w * 4096 + l * 16;
#pragma unroll
      for (int i = 0; i < 4; ++i)
        __builtin_amdgcn_global_load_lds(
            (const __attribute__((address_space(1))) unsigned int*)(gsrc +
                                                                    i * 1024),
            (__attribute__((address_space(3))) unsigned int*)((char*)Bt +
                                                              w * 4096 +
                                                              i * 1024),
            16, 0, 0);
    }
    const int part = kb >> 4;          // 0: f*q, 1: f*m, 2: |f-q|, 3: |f-m|
    const int h0 = (kb & 15) * 32;
    f32x4 fv = *(const f32x4*)(fbase + h0);
    f32x4 ov = (part & 1) ? *(const f32x4*)&mS[h0 + ac * 4]
                          : *(const f32x4*)&qS[h0 + ac * 4];
    float z0, z1, z2, z3;
    if (part < 2) {
      z0 = fv[0] * ov[0]; z1 = fv[1] * ov[1];
      z2 = fv[2] * ov[2]; z3 = fv[3] * ov[3];
    } else {
      z0 = fabsf(fv[0] - ov[0]); z1 = fabsf(fv[1] - ov[1]);
      z2 = fabsf(fv[2] - ov[2]); z3 = fabsf(fv[3] - ov[3]);
    }
    unsigned p0 = (unsigned)f2bf(z0) | ((unsigned)f2bf(z1) << 16);
    unsigned p1 = (unsigned)f2bf(z2) | ((unsigned)f2bf(z3) << 16);
    u32x2 pk = {p0, p1};
    *(u32x2*)&At[arow * 40 + ac * 4] = pk;
    __syncthreads();  // drains DMA (vmcnt) + A-writes (lgkmcnt)
    bf16x8 af[2];
#pragma unroll
    for (int mi = 0; mi < 2; ++mi) {
      i32x4 av = *(const i32x4*)&At[((mgrp * 2 + mi) * 16 + lm) * 40 + lk * 8];
      af[mi] = __builtin_bit_cast(bf16x8, av);
    }
#pragma unroll
    for (int i = 0; i < 8; ++i) {
      const int nt = ngrp * 8 + i;
      i32x4 bv = *(const i32x4*)&Bt[lk * 4096 + (nt * 16 + lm) * 8];
      bf16x8 bf = __builtin_bit_cast(bf16x8, bv);
      acc[0][i] = __builtin_amdgcn_mfma_f32_16x16x32_bf16(af[0], bf, acc[0][i], 0, 0, 0);
      acc[1][i] = __builtin_amdgcn_mfma_f32_16x16x32_bf16(af[1], bf, acc[1][i], 0, 0, 0);
    }
  }
  float pr_[2][4];
#pragma unroll
  for (int mi = 0; mi < 2; ++mi)
#pragma unroll
    for (int r = 0; r < 4; ++r) pr_[mi][r] = 0.f;
#pragma unroll
  for (int i = 0; i < 8; ++i) {
    const int n_i = (ngrp * 8 + i) * 16 + lm;
    const float zb = z1bS[n_i], zw = z2wS[n_i];
#pragma unroll
    for (int mi = 0; mi < 2; ++mi)
#pragma unroll
      for (int r = 0; r < 4; ++r)
        pr_[mi][r] += fast_tanh(acc[mi][i][r] + zb) * zw;
  }
#pragma unroll
  for (int mask = 1; mask < 16; mask <<= 1)
#pragma unroll
    for (int mi = 0; mi < 2; ++mi)
#pragma unroll
      for (int r = 0; r < 4; ++r)
        pr_[mi][r] += __shfl_xor(pr_[mi][r], mask, 64);
  if (lm == 0) {
#pragma unroll
    for (int mi = 0; mi < 2; ++mi)
#pragma unroll
      for (int r = 0; r < 4; ++r)
        lp[((mgrp * 2 + mi) * 16 + lk * 4 + r) * 4 + ngrp] = pr_[mi][r];
  }
  __syncthreads();
  if (tid < 64)
    logits[row0 + tid] =
        lp[tid * 4] + lp[tid * 4 + 1] + lp[tid * 4 + 2] + lp[tid * 4 + 3];
}

// ---------------------------------------------------------------------------
// Softmax over S per batch; output TRANSPOSED: GT[s][b] for coalesced scan loads
// ---------------------------------------------------------------------------
__global__ void k_softmax(const float* __restrict__ logits,
                          float* __restrict__ GT) {
  __shared__ float red[4], red2[4];
  int b = blockIdx.x, t = threadIdx.x;
  float v = logits[b * 256 + t];
  float mx = v;
#pragma unroll
  for (int mask = 1; mask < 64; mask <<= 1)
    mx = fmaxf(mx, __shfl_xor(mx, mask, 64));
  if ((t & 63) == 0) red[t >> 6] = mx;
  __syncthreads();
  mx = fmaxf(fmaxf(red[0], red[1]), fmaxf(red[2], red[3]));
  float e = __expf(v - mx);
  float sm = e;
#pragma unroll
  for (int mask = 1; mask < 64; mask <<= 1) sm += __shfl_xor(sm, mask, 64);
  if ((t & 63) == 0) red2[t >> 6] = sm;
  __syncthreads();
  sm = red2[0] + red2[1] + red2[2] + red2[3];
  GT[t * 128 + b] = e / sm;
}

// ---------------------------------------------------------------------------
// Scan v7: in-register update (no outb), 2 barriers/step.
// 8 groups x 4 members, 16 batches/group, N=128/WG. Wave w computes BOTH
// Ur-tile-w and U-tile-w -> acc0/acc1 hold (C@Ur),(C@U) for the SAME
// (batch,n) per lane (C/D layout: batch=(l>>4)*4+r, n=w*16+(l&15)).
// Publish: pair-pack bf16 via shfl_xor(1), even lanes store dwords.
// Chain: publish -> b2(drain) -> tid0 flag -> all threads poll flag quad ->
// gather 3x8B + own 4x4B LDS writes -> b3. facts/G prefetched 1 step ahead.
// ---------------------------------------------------------------------------
__global__ __launch_bounds__(512, 1) void k_scan(
    const float* __restrict__ facts, const float* __restrict__ GT,
    const unsigned short* __restrict__ PB, const float* __restrict__ rsr,
    const float* __restrict__ rsh, const float* __restrict__ br,
    const float* __restrict__ bur, const float* __restrict__ bw,
    const float* __restrict__ bu, unsigned int* __restrict__ EX,
    unsigned int* __restrict__ FLG, float* __restrict__ Cb) {
  __shared__ unsigned short A[16 * 520];  // 16 rows x 512 bf16, 1040B pitch
  const int tid = threadIdx.x;
  const int g = blockIdx.x & 7;    // group
  const int mem = blockIdx.x >> 3; // member 0..3, n-slice [mem*128, +128)
  const int w = tid >> 6, l = tid & 63;
  const int lm = l & 15, lk = (l >> 4) & 3;
  // zero A
  for (int i = tid; i < 16 * 520 / 4; i += 512) ((u64*)A)[i] = 0ull;
  // weights: wave w owns ntile w for BOTH matrices (128 VGPRs)
  i32x4 bfr[2][16];
  const char* pb = (const char*)PB + (size_t)(mem * 8 + w) * 32768;
#pragma unroll
  for (int mat = 0; mat < 2; ++mat)
#pragma unroll
    for (int kt = 0; kt < 16; ++kt)
      bfr[mat][kt] = *(const i32x4*)(pb + (mat * 16 + kt) * 1024 + l * 16);
  // this lane's (batch,n) in MFMA C/D layout
  const int n = mem * 128 + w * 16 + lm;
  const int b0 = g * 16 + lk * 4;  // batches b0..b0+3 (r = acc reg idx)
  const float c_rsr = rsr[n], c_br = br[n];
  const float c_rsh = rsh[n], c_bw = bw[n];
  const float c_bur = bur[n], c_bu = bu[n];
  const float* fb[4];
#pragma unroll
  for (int r = 0; r < 4; ++r)
    fb[r] = facts + (size_t)(b0 + r) * (256 * 512) + n;
  // gather mapping: thread covers (row = tid>>5, u64-unit = tid&31) per quad
  const int grow = tid >> 5, gcu = tid & 31;
  const u64* EXQ = (const u64*)EX;
  f32x4 Cv = (f32x4){0.f, 0.f, 0.f, 0.f};
  // prefetch s=0 inputs
  float fct[4];
#pragma unroll
  for (int r = 0; r < 4; ++r) fct[r] = fb[r][0];
  f32x4 gvv = *(const f32x4*)(GT + b0);
  __syncthreads();

  for (int s = 0; s < 256; ++s) {
    const unsigned tag = (unsigned)(s + 1);
    const unsigned rbase = ((unsigned)(s & 1) * 8 + (unsigned)g) * 16;
    // ---- matvec: acc0 = (C@Ur) tile, acc1 = (C@U) tile ----
    f32x4 acc0 = (f32x4){0.f, 0.f, 0.f, 0.f};
    f32x4 acc1 = (f32x4){0.f, 0.f, 0.f, 0.f};
#pragma unroll
    for (int kt = 0; kt < 16; ++kt) {
      i32x4 av = *(const i32x4*)&A[lm * 520 + kt * 32 + lk * 8];
      bf16x8 afv = __builtin_bit_cast(bf16x8, av);
      acc0 = __builtin_amdgcn_mfma_f32_16x16x32_bf16(
          afv, __builtin_bit_cast(bf16x8, bfr[0][kt]), acc0, 0, 0, 0);
      acc1 = __builtin_amdgcn_mfma_f32_16x16x32_bf16(
          afv, __builtin_bit_cast(bf16x8, bfr[1][kt]), acc1, 0, 0, 0);
    }
    // ---- in-register elementwise update (lane owns 4 batches x 1 n) ----
    unsigned pkd[4];
#pragma unroll
    for (int r = 0; r < 4; ++r) {
      const float pr = fct[r] * c_rsr + c_br;
      const float ph = fct[r] * c_rsh + c_bw;
      const float r_ = fast_sigmoid(pr + acc0[r] + c_bur);
      const float ht = fast_tanh(ph + r_ * (acc1[r] + c_bu));
      Cv[r] = gvv[r] * ht + (1.0f - gvv[r]) * Cv[r];
      const int mb = (int)f2bf(Cv[r]);
      pkd[r] = (unsigned)mb | ((unsigned)__shfl_xor(mb, 1, 64) << 16);
    }
    // ---- publish: even-n lanes store (n,n+1) dword per batch ----
    if (!(lm & 1)) {
#pragma unroll
      for (int r = 0; r < 4; ++r)
        __hip_atomic_store(EX + (rbase + (unsigned)(lk * 4 + r)) * 256 +
                               ((unsigned)n >> 1),
                           pkd[r], __ATOMIC_RELAXED, __HIP_MEMORY_SCOPE_AGENT);
    }
    // ---- prefetch next step's inputs (land during chain wait) ----
    float fctn[4];
    f32x4 gvn = gvv;
    if (s < 255) {
#pragma unroll
      for (int r = 0; r < 4; ++r) fctn[r] = fb[r][(size_t)(s + 1) * 512];
      gvn = *(const f32x4*)(GT + (s + 1) * 128 + b0);
    } else {
#pragma unroll
      for (int r = 0; r < 4; ++r) fctn[r] = 0.f;
    }
    __syncthreads();  // drains publish stores (vmcnt0); all MFMA A-reads done
    if (tid == 0)
      __hip_atomic_store(FLG + g * 4 + mem, tag, __ATOMIC_RELAXED,
                         __HIP_MEMORY_SCOPE_AGENT);
    // ---- own slice -> A (even-n lanes, 4B pairs) ----
    if (!(lm & 1)) {
#pragma unroll
      for (int r = 0; r < 4; ++r)
        *(unsigned*)((char*)A + (lk * 4 + r) * 1040 + n * 2) = pkd[r];
    }
    // ---- per-thread poll (1-line flag quad) + one-shot gather ----
    {
#pragma unroll
      for (int j = 0; j < 3; ++j) {
        const int q = j + (j >= mem ? 1 : 0);
        int guard = 0;
        while (__hip_atomic_load(FLG + g * 4 + q, __ATOMIC_RELAXED,
                                 __HIP_MEMORY_SCOPE_AGENT) < tag) {
          __builtin_amdgcn_s_sleep(1);
          if (++guard > (1 << 22)) break;  // hang-safety bailout
        }
      }
      u64 wv[3];
#pragma unroll
      for (int j = 0; j < 3; ++j) {
        const int q = j + (j >= mem ? 1 : 0);
        wv[j] = __hip_atomic_load(
            EXQ + (rbase + (unsigned)grow) * 128 + (unsigned)(q * 32 + gcu),
            __ATOMIC_RELAXED, __HIP_MEMORY_SCOPE_AGENT);
      }
#pragma unroll
      for (int j = 0; j < 3; ++j) {
        const int q = j + (j >= mem ? 1 : 0);
        *(u64*)((char*)A + grow * 1040 + q * 256 + gcu * 8) = wv[j];
      }
    }
    __syncthreads();  // A fully assembled for next step
#pragma unroll
    for (int r = 0; r < 4; ++r) fct[r] = fctn[r];
    gvv = gvn;
  }
#pragma unroll
  for (int r = 0; r < 4; ++r) Cb[(size_t)(b0 + r) * 512 + n] = Cv[r];
}

// ---------------------------------------------------------------------------
// Final: out[b] = relu([prevM | C | questions] @ nm_w + nm_b). 2 batches/WG.
// ---------------------------------------------------------------------------
__global__ __launch_bounds__(512) void k_final(
    const float* __restrict__ prevM, const float* __restrict__ questions,
    const float* __restrict__ Cb, const float* __restrict__ nmw,
    const float* __restrict__ nmb, float* __restrict__ out) {
  __shared__ float cc[2][1536];
  const int t = threadIdx.x;
  const int b0 = blockIdx.x * 2;
  for (int i = t; i < 1536; i += 512) {
#pragma unroll
    for (int bi = 0; bi < 2; ++bi) {
      int bbx = b0 + bi;
      float v;
      if (i < 512) v = prevM[bbx * 512 + i];
      else if (i < 1024) v = Cb[bbx * 512 + i - 512];
      else v = questions[bbx * 512 + i - 1024];
      cc[bi][i] = v;
    }
  }
  __syncthreads();
  const int h = t;
  float a0 = nmb[h], a1 = nmb[h];
#pragma unroll 4
  for (int f = 0; f < 1536; ++f) {
    float wv = nmw[f * 512 + h];
    a0 = fmaf(cc[0][f], wv, a0);
    a1 = fmaf(cc[1][f], wv, a1);
  }
  out[(size_t)b0 * 512 + h] = fmaxf(a0, 0.f);
  out[(size_t)(b0 + 1) * 512 + h] = fmaxf(a1, 0.f);
}

// ---------------------------------------------------------------------------
extern "C" void kernel_launch(void* const* d_in, const int* in_sizes, int n_in,
                              void* d_out, int out_size, void* d_ws,
                              size_t ws_size, hipStream_t stream) {
  const float* facts     = (const float*)d_in[0];
  const float* questions = (const float*)d_in[1];
  const float* prevM     = (const float*)d_in[2];
  const float* z1w       = (const float*)d_in[3];
  const float* z1b       = (const float*)d_in[4];
  const float* z2w       = (const float*)d_in[5];
  // d_in[6] = z2_b: softmax shift-invariant, unused (exact)
  const float* Wr        = (const float*)d_in[7];
  const float* br        = (const float*)d_in[8];
  const float* Ur        = (const float*)d_in[9];
  const float* bur       = (const float*)d_in[10];
  const float* W         = (const float*)d_in[11];
  const float* bw        = (const float*)d_in[12];
  const float* U         = (const float*)d_in[13];
  const float* bu        = (const float*)d_in[14];
  const float* nmw       = (const float*)d_in[15];
  const float* nmb       = (const float*)d_in[16];

  char* ws = (char*)d_ws;
  float* GT            = (float*)(ws + OFF_G);
  float* rsr           = (float*)(ws + OFF_RSR);
  float* rsh           = (float*)(ws + OFF_RSH);
  unsigned* FLG        = (unsigned*)(ws + OFF_FLG);
  unsigned* EX         = (unsigned*)(ws + OFF_EX);
  float* Cb            = (float*)(ws + OFF_CBUF);
  float* logits        = (float*)(ws + OFF_LOGITS);
  unsigned short* Bp   = (unsigned short*)(ws + OFF_BP);
  unsigned short* PB   = (unsigned short*)(ws + OFF_PB);

  hipMemsetAsync(FLG, 0, 32 * sizeof(unsigned), stream);
  k_prep_bp<<<2048, 512, 0, stream>>>(z1w, Bp);
  k_prep_pb<<<1024, 512, 0, stream>>>(Ur, U, PB);
  k_prep_rs<<<1024, 256, 0, stream>>>(Wr, W, rsr, rsh);
  k_gate<<<512, 512, 0, stream>>>(facts, questions, prevM, z1b, z2w, Bp, logits);
  k_softmax<<<128, 256, 0, stream>>>(logits, GT);
  k_scan<<<32, 512, 0, stream>>>(facts, GT, PB, rsr, rsh, br, bur, bw, bu, EX,
                                 FLG, Cb);
  k_final<<<64, 512, 0, stream>>>(prevM, questions, Cb, nmw, nmb, (float*)d_out);
}